// Round 12
// baseline (91.946 us; speedup 1.0000x reference)
//
#include <hip/hip_runtime.h>
#include <math.h>

#define N0 200000
#define N1 1024
#define N2 256
#define N3 32
#define NE0 2048000
#define NE1 262144
#define NE2 8192
#define BATCH 32
#define NCLS 10
#define NP 4             // batch planes: plane p holds batch lanes 8p..8p+7
#define PLANE_H2 800000  // h2 elements per plane (200000 rows * 4 h2)

typedef _Float16 h2 __attribute__((ext_vector_type(2)));
typedef _Float16 h8 __attribute__((ext_vector_type(8)));

__device__ __forceinline__ int lower_bound_i(const int* __restrict__ a, int n, int key) {
    int lo = 0, hi = n;
    while (lo < hi) {
        int mid = (lo + hi) >> 1;
        if (a[mid] < key) lo = mid + 1; else hi = mid;
    }
    return lo;
}

// x (32, 200000) fp32 -> 4 batch-planes: xtp[p][s][8] fp16 (plane = 3.2 MB).
// Plane p holds batch lanes 8p..8p+7 of column s as one 16 B h8 row.
__global__ __launch_bounds__(256) void k_transpose(const float* __restrict__ x,
                                                   h2* __restrict__ xtp) {
    __shared__ float tile[32][65];
    const int col0 = blockIdx.x * 64;
    const int tid = threadIdx.x;
    const int c = tid & 63, r0 = tid >> 6;       // 4 row-lanes
    #pragma unroll
    for (int r = r0; r < 32; r += 4) {
        int col = col0 + c;
        tile[r][c] = (col < N0) ? x[r * N0 + col] : 0.f;
    }
    __syncthreads();
    const int bb = (tid & 15) * 2, c0 = tid >> 4; // batches (bb,bb+1), 16 col-lanes
    const int p = bb >> 3;                        // plane
    const int j2 = (bb & 7) >> 1;                 // h2 slot within row
    #pragma unroll
    for (int cc = c0; cc < 64; cc += 16) {
        int col = col0 + cc;
        if (col < N0) {
            h2 v;
            v[0] = (_Float16)tile[bb][cc];
            v[1] = (_Float16)tile[bb + 1][cc];
            xtp[p * PLANE_H2 + col * 4 + j2] = v;
        }
    }
}

// Layer-0 gather, batch-plane bucketed for XCD-L2 residency.
// Block (n, p = blockIdx&3): segment n, plane p. Under round-robin
// blockIdx->XCD, XCD k statically sees only plane k%4 -> each 3.2 MB
// plane stays L2-resident on its 2 XCDs (round-6-verified mapping).
// No edge reordering, no partial buffers: (n,p) owns disjoint 16 B of P0h.
// Deterministic: fixed stride-256 edge order per thread, fixed reduce tree.
__global__ __launch_bounds__(256) void k_gather0v2(const h8* __restrict__ xtp,
                                                   const int* __restrict__ src,
                                                   const int* __restrict__ dst,
                                                   _Float16* __restrict__ p0h) {
    const int p = blockIdx.x & (NP - 1);
    const int n = blockIdx.x >> 2;
    const int e0 = lower_bound_i(dst, NE0, n);
    const int e1 = lower_bound_i(dst, NE0, n + 1);
    const int tid = threadIdx.x;
    const h8* __restrict__ plane = xtp + p * 200000;
    float acc[8] = {0.f, 0.f, 0.f, 0.f, 0.f, 0.f, 0.f, 0.f};
    int e = e0 + tid;
    // 4-deep unroll: 4 independent src->plane chains in flight
    for (; e + 768 < e1; e += 1024) {
        int s0 = src[e];
        int s1 = src[e + 256];
        int s2 = src[e + 512];
        int s3 = src[e + 768];
        h8 v0 = plane[s0];
        h8 v1 = plane[s1];
        h8 v2 = plane[s2];
        h8 v3 = plane[s3];
        #pragma unroll
        for (int i = 0; i < 8; ++i)
            acc[i] += (float)v0[i] + (float)v1[i] + (float)v2[i] + (float)v3[i];
    }
    for (; e < e1; e += 256) {
        h8 v = plane[src[e]];
        #pragma unroll
        for (int i = 0; i < 8; ++i) acc[i] += (float)v[i];
    }
    // wave butterfly (64 lanes) then cross-wave LDS reduce
    #pragma unroll
    for (int off = 1; off < 64; off <<= 1) {
        #pragma unroll
        for (int i = 0; i < 8; ++i) acc[i] += __shfl_xor(acc[i], off);
    }
    __shared__ float red[4][8];
    const int wave = tid >> 6, lane = tid & 63;
    if (lane == 0) {
        #pragma unroll
        for (int i = 0; i < 8; ++i) red[wave][i] = acc[i];
    }
    __syncthreads();
    if (tid < 8) {
        float s = red[0][tid] + red[1][tid] + red[2][tid] + red[3][tid];
        p0h[n * 32 + p * 8 + tid] = (_Float16)s;
    }
}

// Layer-1 segmented gather-sum over fp16 rows (table P0h, 64 KB, L2-resident).
__global__ __launch_bounds__(256) void k_gather1(const h8* __restrict__ table,
                                                 const int* __restrict__ src,
                                                 const int* __restrict__ dst,
                                                 _Float16* __restrict__ out_h,
                                                 float* __restrict__ cnt_out) {
    const int n = blockIdx.x;
    const int e0 = lower_bound_i(dst, NE1, n);
    const int e1 = lower_bound_i(dst, NE1, n + 1);
    const int tid = threadIdx.x;
    const int b4 = tid & 3;
    const int g  = tid >> 2;
    float acc[8] = {0.f, 0.f, 0.f, 0.f, 0.f, 0.f, 0.f, 0.f};
    int e = e0 + g;
    for (; e + 192 < e1; e += 256) {
        int s0 = src[e];
        int s1 = src[e + 64];
        int s2 = src[e + 128];
        int s3 = src[e + 192];
        h8 v0 = table[s0 * 4 + b4];
        h8 v1 = table[s1 * 4 + b4];
        h8 v2 = table[s2 * 4 + b4];
        h8 v3 = table[s3 * 4 + b4];
        #pragma unroll
        for (int i = 0; i < 8; ++i)
            acc[i] += (float)v0[i] + (float)v1[i] + (float)v2[i] + (float)v3[i];
    }
    for (; e < e1; e += 64) {
        int s = src[e];
        h8 v = table[s * 4 + b4];
        #pragma unroll
        for (int i = 0; i < 8; ++i) acc[i] += (float)v[i];
    }
    __shared__ float red[64][33];
    #pragma unroll
    for (int i = 0; i < 8; ++i) red[g][b4 * 8 + i] = acc[i];
    __syncthreads();
    #pragma unroll
    for (int s = 32; s >= 1; s >>= 1) {
        if (g < s) {
            #pragma unroll
            for (int i = 0; i < 8; ++i)
                red[g][b4 * 8 + i] += red[g + s][b4 * 8 + i];
        }
        __syncthreads();
    }
    if (tid < 32) out_h[n * 32 + tid] = (_Float16)red[0][tid];
    else if (tid == 32) cnt_out[n] = (float)(e1 - e0);
}

// Layer-2 gather (32 segments, 16 KB table): writes fp32 S2, T2, cnt2.
__global__ __launch_bounds__(256) void k_gather2(const h8* __restrict__ table,
                                                 const int* __restrict__ src,
                                                 const int* __restrict__ dst,
                                                 const float* __restrict__ cnt_in,
                                                 float* __restrict__ out_f,
                                                 float* __restrict__ cnt_out,
                                                 float* __restrict__ t_out) {
    const int n = blockIdx.x;
    const int e0 = lower_bound_i(dst, NE2, n);
    const int e1 = lower_bound_i(dst, NE2, n + 1);
    const int tid = threadIdx.x;
    const int b4 = tid & 3;
    const int g  = tid >> 2;
    float acc[8] = {0.f, 0.f, 0.f, 0.f, 0.f, 0.f, 0.f, 0.f};
    float tacc = 0.f;
    for (int e = e0 + g; e < e1; e += 64) {
        int s = src[e];
        h8 v = table[s * 4 + b4];
        #pragma unroll
        for (int i = 0; i < 8; ++i) acc[i] += (float)v[i];
        if (b4 == 0) tacc += cnt_in[s];
    }
    __shared__ float red[64][33];
    __shared__ float tred[64];
    #pragma unroll
    for (int i = 0; i < 8; ++i) red[g][b4 * 8 + i] = acc[i];
    if (b4 == 0) tred[g] = tacc;
    __syncthreads();
    #pragma unroll
    for (int s = 32; s >= 1; s >>= 1) {
        if (g < s) {
            #pragma unroll
            for (int i = 0; i < 8; ++i)
                red[g][b4 * 8 + i] += red[g + s][b4 * 8 + i];
            if (b4 == 0) tred[g] += tred[g + s];
        }
        __syncthreads();
    }
    if (tid < 32) out_f[n * 32 + tid] = red[0][tid];
    else if (tid == 32) cnt_out[n] = (float)(e1 - e0);
    else if (tid == 33) t_out[n] = tred[0];
}

// Weight algebra + final output. One block per class k (10 blocks, 256 threads).
// Redundant cheap weight chain per block; one coalesced 16 KB Vfc-row pass.
__global__ __launch_bounds__(256) void k_out(
    const float* __restrict__ V0, const float* __restrict__ g0, const float* __restrict__ b0,
    const float* __restrict__ V1, const float* __restrict__ g1, const float* __restrict__ b1,
    const float* __restrict__ V2, const float* __restrict__ g2, const float* __restrict__ b2,
    const float* __restrict__ Vfc, const float* __restrict__ gfc, const float* __restrict__ bfc,
    const float* __restrict__ S2, const float* __restrict__ T2, const float* __restrict__ cnt2,
    float* __restrict__ out) {
    const int k = blockIdx.x;
    const int tid = threadIdx.x;
    __shared__ float w0[32], u[64], v[64], p[128], q[128], r[128];
    __shared__ float redA[8][32], redB[8][32], redC[8][32], redD[8][32];
    __shared__ float nnred[4];
    __shared__ float M[32];
    __shared__ float scale_s, Kc_s;

    if (tid < 32) {
        float val = V0[tid];
        w0[tid] = g0[tid] * val / fabsf(val);
    }
    __syncthreads();
    if (tid < 64) {
        float nn = 0.f;
        #pragma unroll
        for (int c = 0; c < 32; ++c) { float t = V1[tid * 32 + c]; nn += t * t; }
        float inv = g1[tid] * rsqrtf(nn);
        float su = 0.f, sv = 0.f;
        #pragma unroll
        for (int c = 0; c < 32; ++c) {
            float w = V1[tid * 32 + c] * inv;
            su += w * w0[c]; sv += w * b0[c];
        }
        u[tid] = su; v[tid] = sv;
    }
    __syncthreads();
    if (tid < 128) {
        float nn = 0.f;
        #pragma unroll
        for (int c = 0; c < 64; ++c) { float t = V2[tid * 64 + c]; nn += t * t; }
        float inv = g2[tid] * rsqrtf(nn);
        float sp = 0.f, sq = 0.f, sr = 0.f;
        #pragma unroll
        for (int c = 0; c < 64; ++c) {
            float w = V2[tid * 64 + c] * inv;
            sp += w * u[c]; sq += w * v[c]; sr += w * b1[c];
        }
        p[tid] = sp; q[tid] = sq; r[tid] = sr;
    }
    __syncthreads();

    const int n3 = tid & 31, og = tid >> 5;
    float nn = 0.f, mk = 0.f, mq = 0.f, mr = 0.f, mb = 0.f;
    #pragma unroll
    for (int i = 0; i < 16; ++i) {
        int o = og + 8 * i;
        float w = Vfc[k * 4096 + tid + 256 * i];
        nn += w * w;
        mk += w * p[o]; mq += w * q[o]; mr += w * r[o]; mb += w * b2[o];
    }
    #pragma unroll
    for (int off = 32; off; off >>= 1) nn += __shfl_xor(nn, off);
    if ((tid & 63) == 0) nnred[tid >> 6] = nn;
    redA[og][n3] = mk; redB[og][n3] = mq; redC[og][n3] = mr; redD[og][n3] = mb;
    __syncthreads();
    if (tid == 0) {
        float s = nnred[0] + nnred[1] + nnred[2] + nnred[3];
        scale_s = gfc[k] * rsqrtf(s);
    }
    __syncthreads();
    if (tid < 32) {
        float smk = 0.f, smq = 0.f, smr = 0.f, smb = 0.f;
        #pragma unroll
        for (int i = 0; i < 8; ++i) {
            smk += redA[i][tid]; smq += redB[i][tid];
            smr += redC[i][tid]; smb += redD[i][tid];
        }
        float scale = scale_s;
        M[tid] = scale * smk;
        float kcp = scale * (smq * T2[tid] + smr * cnt2[tid] + smb);
        #pragma unroll
        for (int off = 16; off; off >>= 1) kcp += __shfl_xor(kcp, off);
        if (tid == 0) Kc_s = kcp + bfc[k];
    }
    __syncthreads();
    if (tid < 32) {
        int b = tid;
        float s = 0.f;
        #pragma unroll
        for (int n = 0; n < 32; ++n) s += M[n] * S2[n * 32 + b];
        out[b * NCLS + k] = s + Kc_s;
    }
}

extern "C" void kernel_launch(void* const* d_in, const int* in_sizes, int n_in,
                              void* d_out, int out_size, void* d_ws, size_t ws_size,
                              hipStream_t stream) {
    const float* x   = (const float*)d_in[0];
    const int* src0  = (const int*)d_in[1];
    const int* dst0  = (const int*)d_in[2];
    const int* src1  = (const int*)d_in[3];
    const int* dst1  = (const int*)d_in[4];
    const int* src2  = (const int*)d_in[5];
    const int* dst2  = (const int*)d_in[6];
    const float* V0  = (const float*)d_in[7];
    const float* g0  = (const float*)d_in[8];
    const float* b0  = (const float*)d_in[9];
    const float* V1  = (const float*)d_in[10];
    const float* g1  = (const float*)d_in[11];
    const float* b1  = (const float*)d_in[12];
    const float* V2  = (const float*)d_in[13];
    const float* g2  = (const float*)d_in[14];
    const float* b2  = (const float*)d_in[15];
    const float* Vfc = (const float*)d_in[16];
    const float* gfc = (const float*)d_in[17];
    const float* bfc = (const float*)d_in[18];

    char* ws = (char*)d_ws;
    _Float16* xtp = (_Float16*)(ws);                 // 4 planes = 12,800,000 B
    _Float16* P0h = (_Float16*)(ws + 12800000);      // 65,536 B
    _Float16* S1h = (_Float16*)(ws + 12865536);      // 16,384 B
    float* cnt1   = (float*)(ws + 12881920);         // 1,024 B
    float* S2     = (float*)(ws + 12882944);         // 4,096 B
    float* T2     = (float*)(ws + 12887040);         // 128 B
    float* cnt2   = (float*)(ws + 12887168);         // 128 B

    k_transpose<<<(N0 + 63) / 64, 256, 0, stream>>>(x, (h2*)xtp);
    k_gather0v2<<<N1 * NP, 256, 0, stream>>>((const h8*)xtp, src0, dst0, P0h);
    k_gather1<<<N2, 256, 0, stream>>>((const h8*)P0h, src1, dst1, S1h, cnt1);
    k_gather2<<<N3, 256, 0, stream>>>((const h8*)S1h, src2, dst2, cnt1,
                                      S2, cnt2, T2);
    k_out<<<NCLS, 256, 0, stream>>>(V0, g0, b0, V1, g1, b1, V2, g2, b2,
                                    Vfc, gfc, bfc, S2, T2, cnt2, (float*)d_out);
}

// Round 13
// 85.191 us; speedup vs baseline: 1.0793x; 1.0793x over previous
//
#include <hip/hip_runtime.h>
#include <math.h>

#define N0 200000
#define N1 1024
#define N2 256
#define N3 32
#define NE0 2048000
#define NE1 262144
#define NE2 8192
#define BATCH 32
#define NCLS 10
#define NP 4             // batch planes: plane p holds batch lanes 8p..8p+7
#define PLANE_H2 800000  // h2 elements per plane (200000 rows * 4 h2)
#define TRANS_THREADS 800000  // 3125 blocks * 256

typedef _Float16 h2 __attribute__((ext_vector_type(2)));
typedef _Float16 h8 __attribute__((ext_vector_type(8)));

__device__ __forceinline__ int lower_bound_i(const int* __restrict__ a, int n, int key) {
    int lo = 0, hi = n;
    while (lo < hi) {
        int mid = (lo + hi) >> 1;
        if (a[mid] < key) lo = mid + 1; else hi = mid;
    }
    return lo;
}

// x (32, 200000) fp32 -> 4 batch-planes xtp[p][s][8] fp16 (plane = 3.2 MB).
// ALSO computes off[n] = first edge of dst0-segment n (grid-stride fold;
// independent of the tile work, consumed by the NEXT dispatch).
__global__ __launch_bounds__(256) void k_transpose(const float* __restrict__ x,
                                                   h2* __restrict__ xtp,
                                                   const int* __restrict__ dst0,
                                                   int* __restrict__ off) {
    __shared__ float tile[32][65];
    const int col0 = blockIdx.x * 64;
    const int tid = threadIdx.x;
    const int c = tid & 63, r0 = tid >> 6;       // 4 row-lanes
    #pragma unroll
    for (int r = r0; r < 32; r += 4) {
        int col = col0 + c;
        tile[r][c] = (col < N0) ? x[r * N0 + col] : 0.f;
    }
    __syncthreads();
    const int bb = (tid & 15) * 2, c0 = tid >> 4; // batches (bb,bb+1), 16 col-lanes
    const int p = bb >> 3;                        // plane
    const int j2 = (bb & 7) >> 1;                 // h2 slot within row
    #pragma unroll
    for (int cc = c0; cc < 64; cc += 16) {
        int col = col0 + cc;
        if (col < N0) {
            h2 v;
            v[0] = (_Float16)tile[bb][cc];
            v[1] = (_Float16)tile[bb + 1][cc];
            xtp[p * PLANE_H2 + col * 4 + j2] = v;
        }
    }
    // --- folded segment-bounds pass for dst0 (sorted) ---
    int gtid = blockIdx.x * 256 + tid;
    for (int e = gtid; e < NE0; e += TRANS_THREADS) {
        int d = dst0[e];
        int dp = (e == 0) ? -1 : dst0[e - 1];
        for (int n = dp + 1; n <= d; ++n) off[n] = e;
        if (e == NE0 - 1) {
            for (int n = d + 1; n <= N1; ++n) off[n] = NE0;
        }
    }
}

// Layer-0 gather, batch-plane bucketed, 2 segments per block.
// Block (m, p = blockIdx&3): segments 2m, 2m+1 of plane p. Under round-robin
// blockIdx->XCD, XCD k sees only plane k%4 -> 3.2 MB plane L2-resident on
// XCDs {p, p+4} (round-6/12-verified: FETCH collapses to plane fills).
// ~4000 edges/block -> ~16 edges/thread: 4-deep unroll actually fills.
// Bounds from off[] (no binary search). Per-edge segment = one uniform
// compare; two named acc sets (compile-time indices -> registers).
// Deterministic: fixed stride-256 order, fixed reduce tree.
__global__ __launch_bounds__(256) void k_gather0v3(const h8* __restrict__ xtp,
                                                   const int* __restrict__ src,
                                                   const int* __restrict__ off,
                                                   _Float16* __restrict__ p0h) {
    const int p = blockIdx.x & (NP - 1);
    const int m = blockIdx.x >> 2;
    const int s0 = m * 2;
    const int q0 = off[s0];
    const int t1 = off[s0 + 1];
    const int q1 = off[s0 + 2];
    const int tid = threadIdx.x;
    const h8* __restrict__ plane = xtp + (size_t)p * 200000;
    float a0[8] = {0.f, 0.f, 0.f, 0.f, 0.f, 0.f, 0.f, 0.f};
    float a1[8] = {0.f, 0.f, 0.f, 0.f, 0.f, 0.f, 0.f, 0.f};

#define ACC_EDGE(EE, V)                                                  \
    do {                                                                 \
        if ((EE) < t1) {                                                 \
            _Pragma("unroll") for (int i = 0; i < 8; ++i)                \
                a0[i] += (float)(V)[i];                                  \
        } else {                                                         \
            _Pragma("unroll") for (int i = 0; i < 8; ++i)                \
                a1[i] += (float)(V)[i];                                  \
        }                                                                \
    } while (0)

    int e = q0 + tid;
    for (; e + 768 < q1; e += 1024) {
        int sA = src[e];
        int sB = src[e + 256];
        int sC = src[e + 512];
        int sD = src[e + 768];
        h8 vA = plane[sA];
        h8 vB = plane[sB];
        h8 vC = plane[sC];
        h8 vD = plane[sD];
        ACC_EDGE(e, vA);
        ACC_EDGE(e + 256, vB);
        ACC_EDGE(e + 512, vC);
        ACC_EDGE(e + 768, vD);
    }
    for (; e + 256 < q1; e += 512) {
        int sA = src[e];
        int sB = src[e + 256];
        h8 vA = plane[sA];
        h8 vB = plane[sB];
        ACC_EDGE(e, vA);
        ACC_EDGE(e + 256, vB);
    }
    for (; e < q1; e += 256) {
        h8 v = plane[src[e]];
        ACC_EDGE(e, v);
    }
#undef ACC_EDGE

    // butterfly both acc sets across the 64-lane wave
    #pragma unroll
    for (int o = 1; o < 64; o <<= 1) {
        #pragma unroll
        for (int i = 0; i < 8; ++i) {
            a0[i] += __shfl_xor(a0[i], o);
            a1[i] += __shfl_xor(a1[i], o);
        }
    }
    __shared__ float red[4][2][8];
    const int wave = tid >> 6, lane = tid & 63;
    if (lane == 0) {
        #pragma unroll
        for (int i = 0; i < 8; ++i) {
            red[wave][0][i] = a0[i];
            red[wave][1][i] = a1[i];
        }
    }
    __syncthreads();
    if (tid < 16) {
        int seg = tid >> 3, i = tid & 7;
        float s = red[0][seg][i] + red[1][seg][i] + red[2][seg][i] + red[3][seg][i];
        p0h[(s0 + seg) * 32 + p * 8 + i] = (_Float16)s;
    }
}

// Layer-1 segmented gather-sum over fp16 rows (table P0h, 64 KB, L2-resident).
__global__ __launch_bounds__(256) void k_gather1(const h8* __restrict__ table,
                                                 const int* __restrict__ src,
                                                 const int* __restrict__ dst,
                                                 _Float16* __restrict__ out_h,
                                                 float* __restrict__ cnt_out) {
    const int n = blockIdx.x;
    const int e0 = lower_bound_i(dst, NE1, n);
    const int e1 = lower_bound_i(dst, NE1, n + 1);
    const int tid = threadIdx.x;
    const int b4 = tid & 3;
    const int g  = tid >> 2;
    float acc[8] = {0.f, 0.f, 0.f, 0.f, 0.f, 0.f, 0.f, 0.f};
    int e = e0 + g;
    for (; e + 192 < e1; e += 256) {
        int s0 = src[e];
        int s1 = src[e + 64];
        int s2 = src[e + 128];
        int s3 = src[e + 192];
        h8 v0 = table[s0 * 4 + b4];
        h8 v1 = table[s1 * 4 + b4];
        h8 v2 = table[s2 * 4 + b4];
        h8 v3 = table[s3 * 4 + b4];
        #pragma unroll
        for (int i = 0; i < 8; ++i)
            acc[i] += (float)v0[i] + (float)v1[i] + (float)v2[i] + (float)v3[i];
    }
    for (; e < e1; e += 64) {
        int s = src[e];
        h8 v = table[s * 4 + b4];
        #pragma unroll
        for (int i = 0; i < 8; ++i) acc[i] += (float)v[i];
    }
    __shared__ float red[64][33];
    #pragma unroll
    for (int i = 0; i < 8; ++i) red[g][b4 * 8 + i] = acc[i];
    __syncthreads();
    #pragma unroll
    for (int s = 32; s >= 1; s >>= 1) {
        if (g < s) {
            #pragma unroll
            for (int i = 0; i < 8; ++i)
                red[g][b4 * 8 + i] += red[g + s][b4 * 8 + i];
        }
        __syncthreads();
    }
    if (tid < 32) out_h[n * 32 + tid] = (_Float16)red[0][tid];
    else if (tid == 32) cnt_out[n] = (float)(e1 - e0);
}

// Layer-2 gather (32 segments, 16 KB table): writes fp32 S2, T2, cnt2.
__global__ __launch_bounds__(256) void k_gather2(const h8* __restrict__ table,
                                                 const int* __restrict__ src,
                                                 const int* __restrict__ dst,
                                                 const float* __restrict__ cnt_in,
                                                 float* __restrict__ out_f,
                                                 float* __restrict__ cnt_out,
                                                 float* __restrict__ t_out) {
    const int n = blockIdx.x;
    const int e0 = lower_bound_i(dst, NE2, n);
    const int e1 = lower_bound_i(dst, NE2, n + 1);
    const int tid = threadIdx.x;
    const int b4 = tid & 3;
    const int g  = tid >> 2;
    float acc[8] = {0.f, 0.f, 0.f, 0.f, 0.f, 0.f, 0.f, 0.f};
    float tacc = 0.f;
    for (int e = e0 + g; e < e1; e += 64) {
        int s = src[e];
        h8 v = table[s * 4 + b4];
        #pragma unroll
        for (int i = 0; i < 8; ++i) acc[i] += (float)v[i];
        if (b4 == 0) tacc += cnt_in[s];
    }
    __shared__ float red[64][33];
    __shared__ float tred[64];
    #pragma unroll
    for (int i = 0; i < 8; ++i) red[g][b4 * 8 + i] = acc[i];
    if (b4 == 0) tred[g] = tacc;
    __syncthreads();
    #pragma unroll
    for (int s = 32; s >= 1; s >>= 1) {
        if (g < s) {
            #pragma unroll
            for (int i = 0; i < 8; ++i)
                red[g][b4 * 8 + i] += red[g + s][b4 * 8 + i];
            if (b4 == 0) tred[g] += tred[g + s];
        }
        __syncthreads();
    }
    if (tid < 32) out_f[n * 32 + tid] = red[0][tid];
    else if (tid == 32) cnt_out[n] = (float)(e1 - e0);
    else if (tid == 33) t_out[n] = tred[0];
}

// Weight algebra + final output. One block per class k (10 blocks, 256 threads).
__global__ __launch_bounds__(256) void k_out(
    const float* __restrict__ V0, const float* __restrict__ g0, const float* __restrict__ b0,
    const float* __restrict__ V1, const float* __restrict__ g1, const float* __restrict__ b1,
    const float* __restrict__ V2, const float* __restrict__ g2, const float* __restrict__ b2,
    const float* __restrict__ Vfc, const float* __restrict__ gfc, const float* __restrict__ bfc,
    const float* __restrict__ S2, const float* __restrict__ T2, const float* __restrict__ cnt2,
    float* __restrict__ out) {
    const int k = blockIdx.x;
    const int tid = threadIdx.x;
    __shared__ float w0[32], u[64], v[64], p[128], q[128], r[128];
    __shared__ float redA[8][32], redB[8][32], redC[8][32], redD[8][32];
    __shared__ float nnred[4];
    __shared__ float M[32];
    __shared__ float scale_s, Kc_s;

    if (tid < 32) {
        float val = V0[tid];
        w0[tid] = g0[tid] * val / fabsf(val);
    }
    __syncthreads();
    if (tid < 64) {
        float nn = 0.f;
        #pragma unroll
        for (int c = 0; c < 32; ++c) { float t = V1[tid * 32 + c]; nn += t * t; }
        float inv = g1[tid] * rsqrtf(nn);
        float su = 0.f, sv = 0.f;
        #pragma unroll
        for (int c = 0; c < 32; ++c) {
            float w = V1[tid * 32 + c] * inv;
            su += w * w0[c]; sv += w * b0[c];
        }
        u[tid] = su; v[tid] = sv;
    }
    __syncthreads();
    if (tid < 128) {
        float nn = 0.f;
        #pragma unroll
        for (int c = 0; c < 64; ++c) { float t = V2[tid * 64 + c]; nn += t * t; }
        float inv = g2[tid] * rsqrtf(nn);
        float sp = 0.f, sq = 0.f, sr = 0.f;
        #pragma unroll
        for (int c = 0; c < 64; ++c) {
            float w = V2[tid * 64 + c] * inv;
            sp += w * u[c]; sq += w * v[c]; sr += w * b1[c];
        }
        p[tid] = sp; q[tid] = sq; r[tid] = sr;
    }
    __syncthreads();

    const int n3 = tid & 31, og = tid >> 5;
    float nn = 0.f, mk = 0.f, mq = 0.f, mr = 0.f, mb = 0.f;
    #pragma unroll
    for (int i = 0; i < 16; ++i) {
        int o = og + 8 * i;
        float w = Vfc[k * 4096 + tid + 256 * i];
        nn += w * w;
        mk += w * p[o]; mq += w * q[o]; mr += w * r[o]; mb += w * b2[o];
    }
    #pragma unroll
    for (int off = 32; off; off >>= 1) nn += __shfl_xor(nn, off);
    if ((tid & 63) == 0) nnred[tid >> 6] = nn;
    redA[og][n3] = mk; redB[og][n3] = mq; redC[og][n3] = mr; redD[og][n3] = mb;
    __syncthreads();
    if (tid == 0) {
        float s = nnred[0] + nnred[1] + nnred[2] + nnred[3];
        scale_s = gfc[k] * rsqrtf(s);
    }
    __syncthreads();
    if (tid < 32) {
        float smk = 0.f, smq = 0.f, smr = 0.f, smb = 0.f;
        #pragma unroll
        for (int i = 0; i < 8; ++i) {
            smk += redA[i][tid]; smq += redB[i][tid];
            smr += redC[i][tid]; smb += redD[i][tid];
        }
        float scale = scale_s;
        M[tid] = scale * smk;
        float kcp = scale * (smq * T2[tid] + smr * cnt2[tid] + smb);
        #pragma unroll
        for (int off = 16; off; off >>= 1) kcp += __shfl_xor(kcp, off);
        if (tid == 0) Kc_s = kcp + bfc[k];
    }
    __syncthreads();
    if (tid < 32) {
        int b = tid;
        float s = 0.f;
        #pragma unroll
        for (int n = 0; n < 32; ++n) s += M[n] * S2[n * 32 + b];
        out[b * NCLS + k] = s + Kc_s;
    }
}

extern "C" void kernel_launch(void* const* d_in, const int* in_sizes, int n_in,
                              void* d_out, int out_size, void* d_ws, size_t ws_size,
                              hipStream_t stream) {
    const float* x   = (const float*)d_in[0];
    const int* src0  = (const int*)d_in[1];
    const int* dst0  = (const int*)d_in[2];
    const int* src1  = (const int*)d_in[3];
    const int* dst1  = (const int*)d_in[4];
    const int* src2  = (const int*)d_in[5];
    const int* dst2  = (const int*)d_in[6];
    const float* V0  = (const float*)d_in[7];
    const float* g0  = (const float*)d_in[8];
    const float* b0  = (const float*)d_in[9];
    const float* V1  = (const float*)d_in[10];
    const float* g1  = (const float*)d_in[11];
    const float* b1  = (const float*)d_in[12];
    const float* V2  = (const float*)d_in[13];
    const float* g2  = (const float*)d_in[14];
    const float* b2  = (const float*)d_in[15];
    const float* Vfc = (const float*)d_in[16];
    const float* gfc = (const float*)d_in[17];
    const float* bfc = (const float*)d_in[18];

    char* ws = (char*)d_ws;
    _Float16* xtp = (_Float16*)(ws);                 // 4 planes = 12,800,000 B
    int* off      = (int*)(ws + 12800000);           // 4,100 B (pad to 4,352)
    _Float16* P0h = (_Float16*)(ws + 12804352);      // 65,536 B
    _Float16* S1h = (_Float16*)(ws + 12869888);      // 16,384 B
    float* cnt1   = (float*)(ws + 12886272);         // 1,024 B
    float* S2     = (float*)(ws + 12887296);         // 4,096 B
    float* T2     = (float*)(ws + 12891392);         // 128 B
    float* cnt2   = (float*)(ws + 12891520);         // 128 B

    k_transpose<<<(N0 + 63) / 64, 256, 0, stream>>>(x, (h2*)xtp, dst0, off);
    k_gather0v3<<<(N1 / 2) * NP, 256, 0, stream>>>((const h8*)xtp, src0, off, P0h);
    k_gather1<<<N2, 256, 0, stream>>>((const h8*)P0h, src1, dst1, S1h, cnt1);
    k_gather2<<<N3, 256, 0, stream>>>((const h8*)S1h, src2, dst2, cnt1,
                                      S2, cnt2, T2);
    k_out<<<NCLS, 256, 0, stream>>>(V0, g0, b0, V1, g1, b1, V2, g2, b2,
                                    Vfc, gfc, bfc, S2, T2, cnt2, (float*)d_out);
}

// Round 14
// 79.111 us; speedup vs baseline: 1.1622x; 1.0769x over previous
//
#include <hip/hip_runtime.h>
#include <math.h>

#define N0 200000
#define N1 1024
#define N2 256
#define N3 32
#define NE0 2048000
#define NE1 262144
#define NE2 8192
#define BATCH 32
#define NCLS 10
#define NB 4             // src-range buckets for gather0 (XCD L2 partitioning)
#define SRC_PER_B 50000  // N0 / NB
#define TBLOCKS 3125     // transpose blocks in k_pre

typedef _Float16 h2 __attribute__((ext_vector_type(2)));
typedef _Float16 h8 __attribute__((ext_vector_type(8)));

__device__ __forceinline__ int lower_bound_i(const int* __restrict__ a, int n, int key) {
    int lo = 0, hi = n;
    while (lo < hi) {
        int mid = (lo + hi) >> 1;
        if (a[mid] < key) lo = mid + 1; else hi = mid;
    }
    return lo;
}

// Fused pre-pass: blocks [0,TBLOCKS) transpose x -> xt (200000x32 fp16, 64 B
// rows); blocks [TBLOCKS, TBLOCKS+N1) run the stable 4-way src-bucket
// partition of dst0-segments. The two roles touch disjoint inputs/outputs,
// so they overlap across CUs and the partition cost hides under the
// transpose (both ~10-15 us alone).
__global__ __launch_bounds__(256) void k_pre(const float* __restrict__ x,
                                             h2* __restrict__ xt,
                                             const int* __restrict__ src,
                                             const int* __restrict__ dst,
                                             int* __restrict__ esrc,
                                             int* __restrict__ bstart) {
    const int tid = threadIdx.x;
    if (blockIdx.x < TBLOCKS) {
        // ---- transpose role ----
        __shared__ float tile[32][65];
        const int col0 = blockIdx.x * 64;
        const int c = tid & 63, r0 = tid >> 6;       // 4 row-lanes
        #pragma unroll
        for (int r = r0; r < 32; r += 4) {
            int col = col0 + c;
            tile[r][c] = (col < N0) ? x[r * N0 + col] : 0.f;
        }
        __syncthreads();
        const int bb = (tid & 15) * 2, c0 = tid >> 4; // 16 col-lanes, 2 batches
        #pragma unroll
        for (int cc = c0; cc < 64; cc += 16) {
            int col = col0 + cc;
            if (col < N0) {
                h2 v;
                v[0] = (_Float16)tile[bb][cc];
                v[1] = (_Float16)tile[bb + 1][cc];
                xt[col * 16 + (bb >> 1)] = v;
            }
        }
        return;
    }
    // ---- partition role (one block per dst0 segment) ----
    const int n = blockIdx.x - TBLOCKS;
    const int e0 = lower_bound_i(dst, NE0, n);
    const int e1 = lower_bound_i(dst, NE0, n + 1);
    const int len = e1 - e0;
    const int wave = tid >> 6, lane = tid & 63;
    const int q0 = e0 + (len * wave) / 4;
    const int q1 = e0 + (len * (wave + 1)) / 4;
    __shared__ int wcnt[4][NB];
    __shared__ int wbase[4][NB];

    // phase 1: per-wave bucket counts via ballot (no atomics)
    int c0 = 0, c1 = 0, c2 = 0, c3 = 0;
    for (int base = q0; base < q1; base += 64) {
        int e = base + lane;
        int b = -1;
        if (e < q1) b = src[e] / SRC_PER_B;
        c0 += __popcll(__ballot(b == 0));
        c1 += __popcll(__ballot(b == 1));
        c2 += __popcll(__ballot(b == 2));
        c3 += __popcll(__ballot(b == 3));
    }
    if (lane == 0) { wcnt[wave][0] = c0; wcnt[wave][1] = c1; wcnt[wave][2] = c2; wcnt[wave][3] = c3; }
    __syncthreads();
    if (tid == 0) {
        int acc = e0;
        #pragma unroll
        for (int b = 0; b < NB; ++b) {
            bstart[n * (NB + 1) + b] = acc;
            #pragma unroll
            for (int w = 0; w < 4; ++w) { wbase[w][b] = acc; acc += wcnt[w][b]; }
        }
        bstart[n * (NB + 1) + NB] = acc;   // == e1
    }
    __syncthreads();

    // phase 2: stable scatter (deterministic order), register cursors
    int u0 = wbase[wave][0], u1 = wbase[wave][1], u2 = wbase[wave][2], u3 = wbase[wave][3];
    for (int base = q0; base < q1; base += 64) {
        int e = base + lane;
        int s = 0, b = -1;
        if (e < q1) { s = src[e]; b = s / SRC_PER_B; }
        unsigned long long m0 = __ballot(b == 0);
        unsigned long long m1 = __ballot(b == 1);
        unsigned long long m2 = __ballot(b == 2);
        unsigned long long m3 = __ballot(b == 3);
        unsigned long long lt = (1ull << lane) - 1ull;
        if (b == 0)      esrc[u0 + __popcll(m0 & lt)] = s;
        else if (b == 1) esrc[u1 + __popcll(m1 & lt)] = s;
        else if (b == 2) esrc[u2 + __popcll(m2 & lt)] = s;
        else if (b == 3) esrc[u3 + __popcll(m3 & lt)] = s;
        u0 += __popcll(m0); u1 += __popcll(m1); u2 += __popcll(m2); u3 += __popcll(m3);
    }
}

// Layer-0 gather over bucket-partitioned edges, 64 B rows (1 L2 line/edge).
// Block (n, b): contiguous bucket range; table slice b (3.2 MB) L2-resident
// on XCDs {b, b+4} (blockIdx & 3 == b, round-6-verified mapping). 128 thr,
// 4-deep chains, LDS tree reduce, fp16 partial output (summed by gather1).
__global__ __launch_bounds__(128) void k_gather0s(const h8* __restrict__ table,
                                                  const int* __restrict__ esrc,
                                                  const int* __restrict__ bstart,
                                                  _Float16* __restrict__ p0p) {
    const int b = blockIdx.x & (NB - 1);
    const int n = blockIdx.x >> 2;
    const int q0 = bstart[n * (NB + 1) + b];
    const int q1 = bstart[n * (NB + 1) + b + 1];
    const int tid = threadIdx.x;
    const int b4 = tid & 3;      // which 16B chunk of the 64B row
    const int g  = tid >> 2;     // 32 edge groups
    float acc[8] = {0.f, 0.f, 0.f, 0.f, 0.f, 0.f, 0.f, 0.f};
    int e = q0 + g;
    for (; e + 96 < q1; e += 128) {
        int s0 = esrc[e];
        int s1 = esrc[e + 32];
        int s2 = esrc[e + 64];
        int s3 = esrc[e + 96];
        h8 v0 = table[s0 * 4 + b4];
        h8 v1 = table[s1 * 4 + b4];
        h8 v2 = table[s2 * 4 + b4];
        h8 v3 = table[s3 * 4 + b4];
        #pragma unroll
        for (int i = 0; i < 8; ++i)
            acc[i] += (float)v0[i] + (float)v1[i] + (float)v2[i] + (float)v3[i];
    }
    for (; e < q1; e += 32) {
        int s = esrc[e];
        h8 v = table[s * 4 + b4];
        #pragma unroll
        for (int i = 0; i < 8; ++i) acc[i] += (float)v[i];
    }
    __shared__ float red[32][33];
    #pragma unroll
    for (int i = 0; i < 8; ++i) red[g][b4 * 8 + i] = acc[i];
    __syncthreads();
    #pragma unroll
    for (int s = 16; s >= 1; s >>= 1) {
        if (g < s) {
            #pragma unroll
            for (int i = 0; i < 8; ++i)
                red[g][b4 * 8 + i] += red[g + s][b4 * 8 + i];
        }
        __syncthreads();
    }
    if (tid < 32) p0p[(b * N1 + n) * 32 + tid] = (_Float16)red[0][tid];
}

// Layer-1 gather: per edge, sums the NB fp16 partial planes inline
// (4 x 16 B loads on a 256 KB L1/L2-resident table) -- no reduceP dispatch.
__global__ __launch_bounds__(256) void k_gather1(const h8* __restrict__ p0p,
                                                 const int* __restrict__ src,
                                                 const int* __restrict__ dst,
                                                 _Float16* __restrict__ out_h,
                                                 float* __restrict__ cnt_out) {
    const int n = blockIdx.x;
    const int e0 = lower_bound_i(dst, NE1, n);
    const int e1 = lower_bound_i(dst, NE1, n + 1);
    const int tid = threadIdx.x;
    const int b4 = tid & 3;
    const int g  = tid >> 2;
    float acc[8] = {0.f, 0.f, 0.f, 0.f, 0.f, 0.f, 0.f, 0.f};
    for (int e = e0 + g; e < e1; e += 64) {
        int s = src[e];
        h8 v0 = p0p[0 * N1 * 4 + s * 4 + b4];
        h8 v1 = p0p[1 * N1 * 4 + s * 4 + b4];
        h8 v2 = p0p[2 * N1 * 4 + s * 4 + b4];
        h8 v3 = p0p[3 * N1 * 4 + s * 4 + b4];
        #pragma unroll
        for (int i = 0; i < 8; ++i)
            acc[i] += ((float)v0[i] + (float)v1[i]) + ((float)v2[i] + (float)v3[i]);
    }
    __shared__ float red[64][33];
    #pragma unroll
    for (int i = 0; i < 8; ++i) red[g][b4 * 8 + i] = acc[i];
    __syncthreads();
    #pragma unroll
    for (int s = 32; s >= 1; s >>= 1) {
        if (g < s) {
            #pragma unroll
            for (int i = 0; i < 8; ++i)
                red[g][b4 * 8 + i] += red[g + s][b4 * 8 + i];
        }
        __syncthreads();
    }
    if (tid < 32) out_h[n * 32 + tid] = (_Float16)red[0][tid];
    else if (tid == 32) cnt_out[n] = (float)(e1 - e0);
}

// Layer-2 gather (32 segments, 16 KB table): writes fp32 S2, T2, cnt2.
__global__ __launch_bounds__(256) void k_gather2(const h8* __restrict__ table,
                                                 const int* __restrict__ src,
                                                 const int* __restrict__ dst,
                                                 const float* __restrict__ cnt_in,
                                                 float* __restrict__ out_f,
                                                 float* __restrict__ cnt_out,
                                                 float* __restrict__ t_out) {
    const int n = blockIdx.x;
    const int e0 = lower_bound_i(dst, NE2, n);
    const int e1 = lower_bound_i(dst, NE2, n + 1);
    const int tid = threadIdx.x;
    const int b4 = tid & 3;
    const int g  = tid >> 2;
    float acc[8] = {0.f, 0.f, 0.f, 0.f, 0.f, 0.f, 0.f, 0.f};
    float tacc = 0.f;
    for (int e = e0 + g; e < e1; e += 64) {
        int s = src[e];
        h8 v = table[s * 4 + b4];
        #pragma unroll
        for (int i = 0; i < 8; ++i) acc[i] += (float)v[i];
        if (b4 == 0) tacc += cnt_in[s];
    }
    __shared__ float red[64][33];
    __shared__ float tred[64];
    #pragma unroll
    for (int i = 0; i < 8; ++i) red[g][b4 * 8 + i] = acc[i];
    if (b4 == 0) tred[g] = tacc;
    __syncthreads();
    #pragma unroll
    for (int s = 32; s >= 1; s >>= 1) {
        if (g < s) {
            #pragma unroll
            for (int i = 0; i < 8; ++i)
                red[g][b4 * 8 + i] += red[g + s][b4 * 8 + i];
            if (b4 == 0) tred[g] += tred[g + s];
        }
        __syncthreads();
    }
    if (tid < 32) out_f[n * 32 + tid] = red[0][tid];
    else if (tid == 32) cnt_out[n] = (float)(e1 - e0);
    else if (tid == 33) t_out[n] = tred[0];
}

// Weight algebra + final output. One block per class k (10 blocks, 256 threads).
__global__ __launch_bounds__(256) void k_out(
    const float* __restrict__ V0, const float* __restrict__ g0, const float* __restrict__ b0,
    const float* __restrict__ V1, const float* __restrict__ g1, const float* __restrict__ b1,
    const float* __restrict__ V2, const float* __restrict__ g2, const float* __restrict__ b2,
    const float* __restrict__ Vfc, const float* __restrict__ gfc, const float* __restrict__ bfc,
    const float* __restrict__ S2, const float* __restrict__ T2, const float* __restrict__ cnt2,
    float* __restrict__ out) {
    const int k = blockIdx.x;
    const int tid = threadIdx.x;
    __shared__ float w0[32], u[64], v[64], p[128], q[128], r[128];
    __shared__ float redA[8][32], redB[8][32], redC[8][32], redD[8][32];
    __shared__ float nnred[4];
    __shared__ float M[32];
    __shared__ float scale_s, Kc_s;

    if (tid < 32) {
        float val = V0[tid];
        w0[tid] = g0[tid] * val / fabsf(val);
    }
    __syncthreads();
    if (tid < 64) {
        float nn = 0.f;
        #pragma unroll
        for (int c = 0; c < 32; ++c) { float t = V1[tid * 32 + c]; nn += t * t; }
        float inv = g1[tid] * rsqrtf(nn);
        float su = 0.f, sv = 0.f;
        #pragma unroll
        for (int c = 0; c < 32; ++c) {
            float w = V1[tid * 32 + c] * inv;
            su += w * w0[c]; sv += w * b0[c];
        }
        u[tid] = su; v[tid] = sv;
    }
    __syncthreads();
    if (tid < 128) {
        float nn = 0.f;
        #pragma unroll
        for (int c = 0; c < 64; ++c) { float t = V2[tid * 64 + c]; nn += t * t; }
        float inv = g2[tid] * rsqrtf(nn);
        float sp = 0.f, sq = 0.f, sr = 0.f;
        #pragma unroll
        for (int c = 0; c < 64; ++c) {
            float w = V2[tid * 64 + c] * inv;
            sp += w * u[c]; sq += w * v[c]; sr += w * b1[c];
        }
        p[tid] = sp; q[tid] = sq; r[tid] = sr;
    }
    __syncthreads();

    const int n3 = tid & 31, og = tid >> 5;
    float nn = 0.f, mk = 0.f, mq = 0.f, mr = 0.f, mb = 0.f;
    #pragma unroll
    for (int i = 0; i < 16; ++i) {
        int o = og + 8 * i;
        float w = Vfc[k * 4096 + tid + 256 * i];
        nn += w * w;
        mk += w * p[o]; mq += w * q[o]; mr += w * r[o]; mb += w * b2[o];
    }
    #pragma unroll
    for (int off = 32; off; off >>= 1) nn += __shfl_xor(nn, off);
    if ((tid & 63) == 0) nnred[tid >> 6] = nn;
    redA[og][n3] = mk; redB[og][n3] = mq; redC[og][n3] = mr; redD[og][n3] = mb;
    __syncthreads();
    if (tid == 0) {
        float s = nnred[0] + nnred[1] + nnred[2] + nnred[3];
        scale_s = gfc[k] * rsqrtf(s);
    }
    __syncthreads();
    if (tid < 32) {
        float smk = 0.f, smq = 0.f, smr = 0.f, smb = 0.f;
        #pragma unroll
        for (int i = 0; i < 8; ++i) {
            smk += redA[i][tid]; smq += redB[i][tid];
            smr += redC[i][tid]; smb += redD[i][tid];
        }
        float scale = scale_s;
        M[tid] = scale * smk;
        float kcp = scale * (smq * T2[tid] + smr * cnt2[tid] + smb);
        #pragma unroll
        for (int off = 16; off; off >>= 1) kcp += __shfl_xor(kcp, off);
        if (tid == 0) Kc_s = kcp + bfc[k];
    }
    __syncthreads();
    if (tid < 32) {
        int b = tid;
        float s = 0.f;
        #pragma unroll
        for (int n = 0; n < 32; ++n) s += M[n] * S2[n * 32 + b];
        out[b * NCLS + k] = s + Kc_s;
    }
}

extern "C" void kernel_launch(void* const* d_in, const int* in_sizes, int n_in,
                              void* d_out, int out_size, void* d_ws, size_t ws_size,
                              hipStream_t stream) {
    const float* x   = (const float*)d_in[0];
    const int* src0  = (const int*)d_in[1];
    const int* dst0  = (const int*)d_in[2];
    const int* src1  = (const int*)d_in[3];
    const int* dst1  = (const int*)d_in[4];
    const int* src2  = (const int*)d_in[5];
    const int* dst2  = (const int*)d_in[6];
    const float* V0  = (const float*)d_in[7];
    const float* g0  = (const float*)d_in[8];
    const float* b0  = (const float*)d_in[9];
    const float* V1  = (const float*)d_in[10];
    const float* g1  = (const float*)d_in[11];
    const float* b1  = (const float*)d_in[12];
    const float* V2  = (const float*)d_in[13];
    const float* g2  = (const float*)d_in[14];
    const float* b2  = (const float*)d_in[15];
    const float* Vfc = (const float*)d_in[16];
    const float* gfc = (const float*)d_in[17];
    const float* bfc = (const float*)d_in[18];

    char* ws = (char*)d_ws;
    _Float16* xt   = (_Float16*)(ws);                // 12,800,000 B
    int* esrc      = (int*)(ws + 12800000);          // 8,192,000 B
    int* bstart    = (int*)(ws + 20992000);          // 20,480 B
    _Float16* P0p  = (_Float16*)(ws + 21012480);     // 4*65,536 = 262,144 B
    _Float16* S1h  = (_Float16*)(ws + 21274624);     // 16,384 B
    float* cnt1    = (float*)(ws + 21291008);        // 1,024 B
    float* S2      = (float*)(ws + 21292032);        // 4,096 B
    float* T2      = (float*)(ws + 21296128);        // 128 B
    float* cnt2    = (float*)(ws + 21296256);        // 128 B

    k_pre<<<TBLOCKS + N1, 256, 0, stream>>>(x, (h2*)xt, src0, dst0, esrc, bstart);
    k_gather0s<<<N1 * NB, 128, 0, stream>>>((const h8*)xt, esrc, bstart,
                                            (_Float16*)P0p);
    k_gather1<<<N2, 256, 0, stream>>>((const h8*)P0p, src1, dst1, S1h, cnt1);
    k_gather2<<<N3, 256, 0, stream>>>((const h8*)S1h, src2, dst2, cnt1,
                                      S2, cnt2, T2);
    k_out<<<NCLS, 256, 0, stream>>>(V0, g0, b0, V1, g1, b1, V2, g2, b2,
                                    Vfc, gfc, bfc, S2, T2, cnt2, (float*)d_out);
}